// Round 10
// baseline (351.975 us; speedup 1.0000x reference)
//
#include <hip/hip_runtime.h>
#include <cstdint>

#define TSIZE (1u << 19)
#define MASKU (TSIZE - 1u)
#define P1U 2654435761u

// hierarchical capacity bins:
//  - counters/slots at 16-px granularity (128x128 = 16384 children, mean 128)
//  - children of each 32-px parent contiguous: parent block = 4*144 = 576
//    slots = 9 waves, wave-aligned -> every wave within one 32-px parent
#define CBINS_X 128
#define NCB (CBINS_X * CBINS_X)     // 16384 child bins
#define CAP 144                     // mean 128 + 1.4 sigma; ~6.5K ovf expected
#define SLOTS (NCB * CAP)           // 2,359,296 -> 9216 blocks of 256

// ---------------- embed core (numerics FROZEN since round 2) ----------------
// RES[15] = 2047 (verified round 2). Levels 0-11 direct (fused 16B pair
// gathers); 12-15 hash; reference searchsorted == identity lookup.
// MLP structure: all 40 gathers issued before any lerp.
__device__ __forceinline__ void embed_point(float2 xv, int orig,
                                            const float* __restrict__ tables,
                                            float* __restrict__ out) {
  constexpr int RESV[16] = {16, 22, 30, 42, 58, 80, 111, 153,
                            212, 294, 406, 561, 776, 1072, 1482, 2047};
  const float2* tabs = reinterpret_cast<const float2*>(tables);

  float4 lo[12], hi[12];
  float2 eh[4][4];
  float w0a[16], w1a[16];

#pragma unroll
  for (int l = 0; l < 12; ++l) {
    const int res = RESV[l];
    const float gs = (float)(2048.0 / (double)res);  // f32(double(2048/res))
    float f0 = floorf(xv.x / gs);
    float f1 = floorf(xv.y / gs);
    float g0 = f0 * gs;
    float g1 = f1 * gs;
    w0a[l] = (xv.x - g0) / ((g0 + gs) - g0);
    w1a[l] = (xv.y - g1) / ((g1 + gs) - g1);
    int base = (int)f0 * res + (int)f1;
    const float2* tab = tabs + (size_t)l * TSIZE;
    lo[l] = *reinterpret_cast<const float4*>(tab + base);
    hi[l] = *reinterpret_cast<const float4*>(tab + base + res);
  }
#pragma unroll
  for (int l = 0; l < 4; ++l) {
    const int res = RESV[12 + l];
    const float gs = (float)(2048.0 / (double)res);
    float f0 = floorf(xv.x / gs);
    float f1 = floorf(xv.y / gs);
    float g0 = f0 * gs;
    float g1 = f1 * gs;
    w0a[12 + l] = (xv.x - g0) / ((g0 + gs) - g0);
    w1a[12 + l] = (xv.y - g1) / ((g1 + gs) - g1);
    uint32_t u0 = (uint32_t)(int)f0;
    uint32_t u1m = (uint32_t)(int)f1 * P1U;
    const float2* tab = tabs + (size_t)(12 + l) * TSIZE;
    eh[l][0] = tab[(u0 ^ u1m) & MASKU];
    eh[l][1] = tab[(u0 ^ (u1m + P1U)) & MASKU];
    eh[l][2] = tab[((u0 + 1u) ^ u1m) & MASKU];
    eh[l][3] = tab[((u0 + 1u) ^ (u1m + P1U)) & MASKU];
  }

  float feat[32];
#pragma unroll
  for (int l = 0; l < 12; ++l) {
    float w0 = w0a[l], w1 = w1a[l];
    float omw0 = 1.0f - w0, omw1 = 1.0f - w1;
    float c0x = lo[l].x * omw1 + lo[l].z * w1;
    float c0y = lo[l].y * omw1 + lo[l].w * w1;
    float c1x = hi[l].x * omw1 + hi[l].z * w1;
    float c1y = hi[l].y * omw1 + hi[l].w * w1;
    feat[2 * l]     = c0x * omw0 + c1x * w0;
    feat[2 * l + 1] = c0y * omw0 + c1y * w0;
  }
#pragma unroll
  for (int l = 0; l < 4; ++l) {
    float w0 = w0a[12 + l], w1 = w1a[12 + l];
    float omw0 = 1.0f - w0, omw1 = 1.0f - w1;
    float c0x = eh[l][0].x * omw1 + eh[l][1].x * w1;
    float c0y = eh[l][0].y * omw1 + eh[l][1].y * w1;
    float c1x = eh[l][2].x * omw1 + eh[l][3].x * w1;
    float c1y = eh[l][2].y * omw1 + eh[l][3].y * w1;
    feat[24 + 2 * l]     = c0x * omw0 + c1x * w0;
    feat[24 + 2 * l + 1] = c0y * omw0 + c1y * w0;
  }

  float4* o = reinterpret_cast<float4*>(out) + (size_t)orig * 8;
#pragma unroll
  for (int j = 0; j < 8; ++j) {
    o[j] = make_float4(feat[4 * j], feat[4 * j + 1], feat[4 * j + 2], feat[4 * j + 3]);
  }
}

// ---------------- hierarchical capacity-bin sort (SoA records) --------------

// child index: 4 children of each 32-px parent are contiguous
__device__ __forceinline__ int child_of(float2 xv) {
  int bx = min((int)(xv.x * 0.0625f), CBINS_X - 1);   // 16-px coords
  int by = min((int)(xv.y * 0.0625f), CBINS_X - 1);
  int parent = ((bx >> 1) << 6) + (by >> 1);          // 64x64 parents
  int quad = ((bx & 1) << 1) + (by & 1);
  return (parent << 2) + quad;
}

__global__ __launch_bounds__(256) void scatter_cap(
    const float2* __restrict__ xs, int* __restrict__ cnt,
    float2* __restrict__ scoord, int* __restrict__ sidx,
    int* __restrict__ ovf, int* __restrict__ ovf_cnt, int B) {
  int p = blockIdx.x * 256 + threadIdx.x;
  if (p >= B) return;
  float2 xv = xs[p];
  int child = child_of(xv);
  int pos = atomicAdd(&cnt[child], 1);
  if (pos < CAP) {
    int slot = child * CAP + pos;
    scoord[slot] = xv;   // 8B store (proven format)
    sidx[slot] = p;      // 4B store (proven format)
  } else {
    int o = atomicAdd(ovf_cnt, 1);
    ovf[o] = p;  // ovf capacity == B: can never overflow
  }
}

__global__ __launch_bounds__(256, 2) void hashenc_cap(
    const float2* __restrict__ scoord, const int* __restrict__ sidx,
    const int* __restrict__ cnt,
    const float* __restrict__ tables, float* __restrict__ out) {
  int bid = blockIdx.x;
  int nb = gridDim.x;  // 9216, divisible by 8
  int chunk = nb >> 3;
  bid = (bid & 7) * chunk + (bid >> 3);   // XCD slab swizzle (bijective)
  int slot = bid * 256 + threadIdx.x;
  int child = slot / CAP;                 // const divisor -> magic mul
  int pos = slot - child * CAP;
  int c = cnt[child];
  if (pos >= min(c, CAP)) return;
  float2 xv = scoord[slot];               // slot-coalesced 8B read
  int orig = sidx[slot];                  // slot-coalesced 4B read
  embed_point(xv, orig, tables, out);
}

__global__ __launch_bounds__(256) void ovf_kernel(
    const float2* __restrict__ xs, const int* __restrict__ ovf,
    const int* __restrict__ ovf_cnt, const float* __restrict__ tables,
    float* __restrict__ out) {
  int n = *ovf_cnt;
  for (int i = blockIdx.x * 256 + threadIdx.x; i < n; i += gridDim.x * 256) {
    int p = ovf[i];
    embed_point(xs[p], p, tables, out);
  }
}

// ---------------- unsorted fallback -----------------------------------------

__global__ __launch_bounds__(256, 2) void hashenc_plain(
    const float2* __restrict__ xs, const float* __restrict__ tables,
    float* __restrict__ out, int B) {
  int p = blockIdx.x * 256 + threadIdx.x;
  if (p >= B) return;
  embed_point(xs[p], p, tables, out);
}

// ---------------- launch ----------------------------------------------------

extern "C" void kernel_launch(void* const* d_in, const int* in_sizes, int n_in,
                              void* d_out, int out_size, void* d_ws, size_t ws_size,
                              hipStream_t stream) {
  const float2* xs = (const float2*)d_in[0];
  const float* tables = (const float*)d_in[1];
  float* out = (float*)d_out;
  int B = in_sizes[0] / 2;
  int blocks = (B + 255) / 256;
  char* ws = (char*)d_ws;

  // layout: scoord (8B*SLOTS) | sidx (4B*SLOTS) | ovf (4B*B) | cnt (4B*NCB) | ovf_cnt
  size_t c_sco = 0;
  size_t c_sid = c_sco + (size_t)SLOTS * 8;
  size_t c_ovf = c_sid + (size_t)SLOTS * 4;
  size_t c_cnt = c_ovf + (size_t)B * 4;
  size_t c_ocnt = c_cnt + (size_t)NCB * 4;
  size_t need = c_ocnt + 64;

  bool grid_ok = (blocks & 7) == 0;
  if (grid_ok && ws_size >= need) {
    float2* scoord = (float2*)(ws + c_sco);
    int* sidx = (int*)(ws + c_sid);
    int* ovf = (int*)(ws + c_ovf);
    int* cnt = (int*)(ws + c_cnt);
    int* ovf_cnt = (int*)(ws + c_ocnt);
    hipMemsetAsync(cnt, 0, (size_t)NCB * 4 + 64, stream);  // cnt + ovf_cnt contiguous
    hipLaunchKernelGGL(scatter_cap, dim3(blocks), dim3(256), 0, stream,
                       xs, cnt, scoord, sidx, ovf, ovf_cnt, B);
    hipLaunchKernelGGL(hashenc_cap, dim3(SLOTS / 256), dim3(256), 0, stream,
                       scoord, sidx, cnt, tables, out);
    hipLaunchKernelGGL(ovf_kernel, dim3(32), dim3(256), 0, stream,
                       xs, ovf, ovf_cnt, tables, out);
  } else {
    hipLaunchKernelGGL(hashenc_plain, dim3(blocks), dim3(256), 0, stream,
                       xs, tables, out, B);
  }
}

// Round 11
// 316.404 us; speedup vs baseline: 1.1124x; 1.1124x over previous
//
#include <hip/hip_runtime.h>
#include <cstdint>

#define TSIZE (1u << 19)
#define MASKU (TSIZE - 1u)
#define P1U 2654435761u

// hierarchical capacity bins:
//  - counters/slots at 16-px granularity (128x128 = 16384 children, mean 128)
//  - children of each 32-px parent contiguous: parent block = 4*144 = 576
//    slots = 9 waves, wave-aligned -> every wave within one 32-px parent
//  - records AoS float4 (round-6 proven format) -- A/B vs round 10's SoA
#define CBINS_X 128
#define NCB (CBINS_X * CBINS_X)     // 16384 child bins
#define CAP 144                     // mean 128 + 1.4 sigma; ~6.5K ovf expected
#define SLOTS (NCB * CAP)           // 2,359,296 -> 9216 blocks of 256

// ---------------- embed core (numerics FROZEN since round 2) ----------------
// RES[15] = 2047 (verified round 2). Levels 0-11 direct (fused 16B pair
// gathers); 12-15 hash; reference searchsorted == identity lookup.
// MLP structure: all 40 gathers issued before any lerp.
__device__ __forceinline__ void embed_point(float2 xv, int orig,
                                            const float* __restrict__ tables,
                                            float* __restrict__ out) {
  constexpr int RESV[16] = {16, 22, 30, 42, 58, 80, 111, 153,
                            212, 294, 406, 561, 776, 1072, 1482, 2047};
  const float2* tabs = reinterpret_cast<const float2*>(tables);

  float4 lo[12], hi[12];
  float2 eh[4][4];
  float w0a[16], w1a[16];

#pragma unroll
  for (int l = 0; l < 12; ++l) {
    const int res = RESV[l];
    const float gs = (float)(2048.0 / (double)res);  // f32(double(2048/res))
    float f0 = floorf(xv.x / gs);
    float f1 = floorf(xv.y / gs);
    float g0 = f0 * gs;
    float g1 = f1 * gs;
    w0a[l] = (xv.x - g0) / ((g0 + gs) - g0);
    w1a[l] = (xv.y - g1) / ((g1 + gs) - g1);
    int base = (int)f0 * res + (int)f1;
    const float2* tab = tabs + (size_t)l * TSIZE;
    lo[l] = *reinterpret_cast<const float4*>(tab + base);
    hi[l] = *reinterpret_cast<const float4*>(tab + base + res);
  }
#pragma unroll
  for (int l = 0; l < 4; ++l) {
    const int res = RESV[12 + l];
    const float gs = (float)(2048.0 / (double)res);
    float f0 = floorf(xv.x / gs);
    float f1 = floorf(xv.y / gs);
    float g0 = f0 * gs;
    float g1 = f1 * gs;
    w0a[12 + l] = (xv.x - g0) / ((g0 + gs) - g0);
    w1a[12 + l] = (xv.y - g1) / ((g1 + gs) - g1);
    uint32_t u0 = (uint32_t)(int)f0;
    uint32_t u1m = (uint32_t)(int)f1 * P1U;
    const float2* tab = tabs + (size_t)(12 + l) * TSIZE;
    eh[l][0] = tab[(u0 ^ u1m) & MASKU];
    eh[l][1] = tab[(u0 ^ (u1m + P1U)) & MASKU];
    eh[l][2] = tab[((u0 + 1u) ^ u1m) & MASKU];
    eh[l][3] = tab[((u0 + 1u) ^ (u1m + P1U)) & MASKU];
  }

  float feat[32];
#pragma unroll
  for (int l = 0; l < 12; ++l) {
    float w0 = w0a[l], w1 = w1a[l];
    float omw0 = 1.0f - w0, omw1 = 1.0f - w1;
    float c0x = lo[l].x * omw1 + lo[l].z * w1;
    float c0y = lo[l].y * omw1 + lo[l].w * w1;
    float c1x = hi[l].x * omw1 + hi[l].z * w1;
    float c1y = hi[l].y * omw1 + hi[l].w * w1;
    feat[2 * l]     = c0x * omw0 + c1x * w0;
    feat[2 * l + 1] = c0y * omw0 + c1y * w0;
  }
#pragma unroll
  for (int l = 0; l < 4; ++l) {
    float w0 = w0a[12 + l], w1 = w1a[12 + l];
    float omw0 = 1.0f - w0, omw1 = 1.0f - w1;
    float c0x = eh[l][0].x * omw1 + eh[l][1].x * w1;
    float c0y = eh[l][0].y * omw1 + eh[l][1].y * w1;
    float c1x = eh[l][2].x * omw1 + eh[l][3].x * w1;
    float c1y = eh[l][2].y * omw1 + eh[l][3].y * w1;
    feat[24 + 2 * l]     = c0x * omw0 + c1x * w0;
    feat[24 + 2 * l + 1] = c0y * omw0 + c1y * w0;
  }

  float4* o = reinterpret_cast<float4*>(out) + (size_t)orig * 8;
#pragma unroll
  for (int j = 0; j < 8; ++j) {
    o[j] = make_float4(feat[4 * j], feat[4 * j + 1], feat[4 * j + 2], feat[4 * j + 3]);
  }
}

// ---------------- hierarchical capacity-bin sort (AoS float4 records) -------

// child index: 4 children of each 32-px parent are contiguous
__device__ __forceinline__ int child_of(float2 xv) {
  int bx = min((int)(xv.x * 0.0625f), CBINS_X - 1);   // 16-px coords
  int by = min((int)(xv.y * 0.0625f), CBINS_X - 1);
  int parent = ((bx >> 1) << 6) + (by >> 1);          // 64x64 parents
  int quad = ((bx & 1) << 1) + (by & 1);
  return (parent << 2) + quad;
}

__global__ __launch_bounds__(256) void scatter_cap(
    const float2* __restrict__ xs, int* __restrict__ cnt,
    float4* __restrict__ recs,
    int* __restrict__ ovf, int* __restrict__ ovf_cnt, int B) {
  int p = blockIdx.x * 256 + threadIdx.x;
  if (p >= B) return;
  float2 xv = xs[p];
  int child = child_of(xv);
  int pos = atomicAdd(&cnt[child], 1);
  if (pos < CAP) {
    recs[child * CAP + pos] = make_float4(xv.x, xv.y, __int_as_float(p), 0.0f);
  } else {
    int o = atomicAdd(ovf_cnt, 1);
    ovf[o] = p;  // ovf capacity == B: can never overflow
  }
}

__global__ __launch_bounds__(256, 2) void hashenc_cap(
    const float4* __restrict__ recs, const int* __restrict__ cnt,
    const float* __restrict__ tables, float* __restrict__ out) {
  int bid = blockIdx.x;
  int nb = gridDim.x;  // 9216, divisible by 8
  int chunk = nb >> 3;
  bid = (bid & 7) * chunk + (bid >> 3);   // XCD slab swizzle (bijective)
  int slot = bid * 256 + threadIdx.x;
  int child = slot / CAP;                 // const divisor -> magic mul
  int pos = slot - child * CAP;
  int c = cnt[child];
  if (pos >= min(c, CAP)) return;
  float4 r = recs[slot];                  // slot-coalesced 16B read
  embed_point(make_float2(r.x, r.y), __float_as_int(r.z), tables, out);
}

__global__ __launch_bounds__(256) void ovf_kernel(
    const float2* __restrict__ xs, const int* __restrict__ ovf,
    const int* __restrict__ ovf_cnt, const float* __restrict__ tables,
    float* __restrict__ out) {
  int n = *ovf_cnt;
  for (int i = blockIdx.x * 256 + threadIdx.x; i < n; i += gridDim.x * 256) {
    int p = ovf[i];
    embed_point(xs[p], p, tables, out);
  }
}

// ---------------- unsorted fallback -----------------------------------------

__global__ __launch_bounds__(256, 2) void hashenc_plain(
    const float2* __restrict__ xs, const float* __restrict__ tables,
    float* __restrict__ out, int B) {
  int p = blockIdx.x * 256 + threadIdx.x;
  if (p >= B) return;
  embed_point(xs[p], p, tables, out);
}

// ---------------- launch ----------------------------------------------------

extern "C" void kernel_launch(void* const* d_in, const int* in_sizes, int n_in,
                              void* d_out, int out_size, void* d_ws, size_t ws_size,
                              hipStream_t stream) {
  const float2* xs = (const float2*)d_in[0];
  const float* tables = (const float*)d_in[1];
  float* out = (float*)d_out;
  int B = in_sizes[0] / 2;
  int blocks = (B + 255) / 256;
  char* ws = (char*)d_ws;

  // layout: recs (16B*SLOTS) | ovf (4B*B) | cnt (4B*NCB) | ovf_cnt (+pad)
  size_t c_recs = 0;
  size_t c_ovf = c_recs + (size_t)SLOTS * 16;
  size_t c_cnt = c_ovf + (size_t)B * 4;
  size_t c_ocnt = c_cnt + (size_t)NCB * 4;
  size_t need = c_ocnt + 64;

  bool grid_ok = (blocks & 7) == 0;
  if (grid_ok && ws_size >= need) {
    float4* recs = (float4*)(ws + c_recs);
    int* ovf = (int*)(ws + c_ovf);
    int* cnt = (int*)(ws + c_cnt);
    int* ovf_cnt = (int*)(ws + c_ocnt);
    hipMemsetAsync(cnt, 0, (size_t)NCB * 4 + 64, stream);  // cnt + ovf_cnt contiguous
    hipLaunchKernelGGL(scatter_cap, dim3(blocks), dim3(256), 0, stream,
                       xs, cnt, recs, ovf, ovf_cnt, B);
    hipLaunchKernelGGL(hashenc_cap, dim3(SLOTS / 256), dim3(256), 0, stream,
                       recs, cnt, tables, out);
    hipLaunchKernelGGL(ovf_kernel, dim3(32), dim3(256), 0, stream,
                       xs, ovf, ovf_cnt, tables, out);
  } else {
    hipLaunchKernelGGL(hashenc_plain, dim3(blocks), dim3(256), 0, stream,
                       xs, tables, out, B);
  }
}